// Round 11
// baseline (302.762 us; speedup 1.0000x reference)
//
#include <hip/hip_runtime.h>
#include <hip/hip_bf16.h>
#include <math.h>

#define DIM 64
#define GNUM 256
#define CNUM 10

// bf16x2 pack/unpack (RNE). All intermediates (h, layer outputs) are bf16 for
// traffic; alpha/softmax math stays f32 (as_/ad_ from f32 accumulators).
__device__ __forceinline__ unsigned bfpack(float a, float b) {
    unsigned ua = __builtin_bit_cast(unsigned, a);
    unsigned ub = __builtin_bit_cast(unsigned, b);
    ua += 0x7fffu + ((ua >> 16) & 1u);
    ub += 0x7fffu + ((ub >> 16) & 1u);
    return (ua >> 16) | (ub & 0xffff0000u);
}
__device__ __forceinline__ float bflo(unsigned u) { return __builtin_bit_cast(float, u << 16); }
__device__ __forceinline__ float bfhi(unsigned u) { return __builtin_bit_cast(float, u & 0xffff0000u); }
__device__ __forceinline__ float bfs(unsigned short u) { return __builtin_bit_cast(float, (unsigned)u << 16); }

// ---------------- CSR build ----------------
__global__ void deg_rank_kernel(const int* __restrict__ ei, int E, int N,
                                int* __restrict__ deg, int* __restrict__ rank) {
    int i = blockIdx.x * blockDim.x + threadIdx.x;
    int EP = E + N;
    if (i >= EP) return;
    int d = (i < E) ? ei[E + i] : (i - E);   // row 1 of edge_index = dst; self loops appended
    rank[i] = atomicAdd(&deg[d], 1);
}

// scan_blocks + graph_bounds, role-split by blockIdx.
__global__ __launch_bounds__(256) void scan_misc(const int* __restrict__ deg, int* __restrict__ part, int n, int nb,
                                                 const int* __restrict__ batch, int N,
                                                 int* __restrict__ gstart) {
    int bid = blockIdx.x;
    if (bid < nb) {
        __shared__ int ws[4];
        int i = bid * 256 + threadIdx.x;
        int v = (i < n) ? deg[i] : 0;
        #pragma unroll
        for (int d = 32; d >= 1; d >>= 1) v += __shfl_xor(v, d);
        if ((threadIdx.x & 63) == 0) ws[threadIdx.x >> 6] = v;
        __syncthreads();
        if (threadIdx.x == 0) part[bid] = ws[0] + ws[1] + ws[2] + ws[3];
    } else {
        for (int g = threadIdx.x; g <= GNUM; g += 256) {
            int lo = 0, hi = N;
            while (lo < hi) { int mid = (lo + hi) >> 1; if (batch[mid] < g) lo = mid + 1; else hi = mid; }
            gstart[g] = lo;
        }
    }
}

// scan_down with the top-level scan fused (nb <= 256 for N <= 65536).
__global__ __launch_bounds__(256) void scan_down(const int* __restrict__ deg, const int* __restrict__ part,
                                                 int* __restrict__ offs, int n) {
    __shared__ int ws[4];
    __shared__ int base_s;
    int tid = threadIdx.x, lane = tid & 63, wid = tid >> 6;
    int pv = (tid < (int)blockIdx.x) ? part[tid] : 0;
    #pragma unroll
    for (int d = 32; d >= 1; d >>= 1) pv += __shfl_xor(pv, d);
    if (lane == 0) ws[wid] = pv;
    __syncthreads();
    if (tid == 0) base_s = ws[0] + ws[1] + ws[2] + ws[3];
    __syncthreads();
    int i = blockIdx.x * 256 + tid;
    int v = (i < n) ? deg[i] : 0;
    int x = v;
    #pragma unroll
    for (int d = 1; d < 64; d <<= 1) { int t = __shfl_up(x, d); if (lane >= d) x += t; }
    if (lane == 63) ws[wid] = x;
    __syncthreads();
    int add = base_s;
    for (int w = 0; w < wid; ++w) add += ws[w];
    if (i < n) offs[i] = add + x - v;
    if (i == n - 1) offs[n] = add + x;
}

// ---------------- per-edge softmax weights (edge-parallel, latency-tolerant) ----------------
// R11: moves the random as_/ad_ gathers + expf OFF gat_agg's per-node critical
// path into an 850k-thread map kernel (gathers hit the 200KB L2-resident
// tables; fully hidden by TLP). we[] is written in csr order -> gat_agg
// reads it coalesced.
__global__ void edge_w(const int* __restrict__ csr, const int* __restrict__ cdst,
                       const float* __restrict__ as_, const float* __restrict__ ad_,
                       float* __restrict__ we, int M) {
    int i = blockIdx.x * blockDim.x + threadIdx.x;
    if (i >= M) return;
    float e = as_[csr[i]] + ad_[cdst[i]];
    e = (e > 0.f) ? e : 0.2f * e;
    we[i] = expf(e);   // no max-subtraction: e bounded (l2-normed inputs), R8-validated
}

// ---------------- tiled mm body ----------------
// 64x64 tile per block; x transposed into LDS (stride 68 floats). 4x4 register
// tile per thread. Input either f32 (layer 1) or packed bf16 (layers 2,3);
// h output always packed bf16 (R7: halves dominant gather traffic).
#define XSTR 68
template<bool BF16IN>
__device__ __forceinline__ void mm_tile_body(int bid,
                                             const void* __restrict__ in_, const float* __restrict__ W,
                                             const float* __restrict__ a_s, const float* __restrict__ a_d,
                                             unsigned* __restrict__ hb, float* __restrict__ as_,
                                             float* __restrict__ ad_, int N) {
    __shared__ float Ws[DIM * DIM];
    __shared__ float xT[XSTR * DIM];
    int tid = threadIdx.x;
    int base = bid * 64;

    const float4* W4 = (const float4*)W;
    float4* Ws4 = (float4*)Ws;
    #pragma unroll
    for (int i = 0; i < 4; ++i) Ws4[tid + 256 * i] = W4[tid + 256 * i];

    {
        int row = tid >> 2;
        int kb = (tid & 3) << 4;
        int grow = base + row;
        int crow = grow < N ? grow : N - 1;
        if (BF16IN) {
            const unsigned* xr = (const unsigned*)in_ + ((size_t)crow << 5) + (kb >> 1);
            uint4 u0 = *(const uint4*)xr;
            uint4 u1 = *(const uint4*)(xr + 4);
            xT[(kb + 0) * XSTR + row] = bflo(u0.x);  xT[(kb + 1) * XSTR + row] = bfhi(u0.x);
            xT[(kb + 2) * XSTR + row] = bflo(u0.y);  xT[(kb + 3) * XSTR + row] = bfhi(u0.y);
            xT[(kb + 4) * XSTR + row] = bflo(u0.z);  xT[(kb + 5) * XSTR + row] = bfhi(u0.z);
            xT[(kb + 6) * XSTR + row] = bflo(u0.w);  xT[(kb + 7) * XSTR + row] = bfhi(u0.w);
            xT[(kb + 8) * XSTR + row] = bflo(u1.x);  xT[(kb + 9) * XSTR + row] = bfhi(u1.x);
            xT[(kb + 10) * XSTR + row] = bflo(u1.y); xT[(kb + 11) * XSTR + row] = bfhi(u1.y);
            xT[(kb + 12) * XSTR + row] = bflo(u1.z); xT[(kb + 13) * XSTR + row] = bfhi(u1.z);
            xT[(kb + 14) * XSTR + row] = bflo(u1.w); xT[(kb + 15) * XSTR + row] = bfhi(u1.w);
        } else {
            const float4* xr = (const float4*)((const float*)in_ + ((size_t)crow << 6) + kb);
            float4 v0 = xr[0], v1 = xr[1], v2 = xr[2], v3 = xr[3];
            xT[(kb + 0) * XSTR + row] = v0.x;  xT[(kb + 1) * XSTR + row] = v0.y;
            xT[(kb + 2) * XSTR + row] = v0.z;  xT[(kb + 3) * XSTR + row] = v0.w;
            xT[(kb + 4) * XSTR + row] = v1.x;  xT[(kb + 5) * XSTR + row] = v1.y;
            xT[(kb + 6) * XSTR + row] = v1.z;  xT[(kb + 7) * XSTR + row] = v1.w;
            xT[(kb + 8) * XSTR + row] = v2.x;  xT[(kb + 9) * XSTR + row] = v2.y;
            xT[(kb + 10) * XSTR + row] = v2.z; xT[(kb + 11) * XSTR + row] = v2.w;
            xT[(kb + 12) * XSTR + row] = v3.x; xT[(kb + 13) * XSTR + row] = v3.y;
            xT[(kb + 14) * XSTR + row] = v3.z; xT[(kb + 15) * XSTR + row] = v3.w;
        }
    }
    __syncthreads();

    int tx = tid & 15, ty = tid >> 4;
    int c0 = tx << 2, r0 = ty << 2;
    float acc[4][4] = {{0.f}};
    #pragma unroll 8
    for (int k = 0; k < DIM; ++k) {
        float4 xv = *(const float4*)(xT + k * XSTR + r0);
        float4 wv = *(const float4*)(Ws + k * DIM + c0);
        acc[0][0] += xv.x * wv.x; acc[0][1] += xv.x * wv.y; acc[0][2] += xv.x * wv.z; acc[0][3] += xv.x * wv.w;
        acc[1][0] += xv.y * wv.x; acc[1][1] += xv.y * wv.y; acc[1][2] += xv.y * wv.z; acc[1][3] += xv.y * wv.w;
        acc[2][0] += xv.z * wv.x; acc[2][1] += xv.z * wv.y; acc[2][2] += xv.z * wv.z; acc[2][3] += xv.z * wv.w;
        acc[3][0] += xv.w * wv.x; acc[3][1] += xv.w * wv.y; acc[3][2] += xv.w * wv.z; acc[3][3] += xv.w * wv.w;
    }

    float4 av = *(const float4*)(a_s + c0);
    float4 dv = *(const float4*)(a_d + c0);
    #pragma unroll
    for (int ri = 0; ri < 4; ++ri) {
        int grow = base + r0 + ri;
        float s1 = acc[ri][0] * av.x + acc[ri][1] * av.y + acc[ri][2] * av.z + acc[ri][3] * av.w;
        float s2 = acc[ri][0] * dv.x + acc[ri][1] * dv.y + acc[ri][2] * dv.z + acc[ri][3] * dv.w;
        #pragma unroll
        for (int d = 1; d <= 8; d <<= 1) { s1 += __shfl_xor(s1, d); s2 += __shfl_xor(s2, d); }
        if (grow < N) {
            uint2 o;
            o.x = bfpack(acc[ri][0], acc[ri][1]);
            o.y = bfpack(acc[ri][2], acc[ri][3]);
            *(uint2*)(hb + ((size_t)grow << 5) + (tx << 1)) = o;
            if (tx == 0) { as_[grow] = s1; ad_[grow] = s2; }
        }
    }
}

__global__ __launch_bounds__(256) void mm_tile_bf(const unsigned* __restrict__ in, const float* __restrict__ W,
                                                  const float* __restrict__ a_s, const float* __restrict__ a_d,
                                                  unsigned* __restrict__ hb, float* __restrict__ as_,
                                                  float* __restrict__ ad_, int N) {
    mm_tile_body<true>(blockIdx.x, in, W, a_s, a_d, hb, as_, ad_, N);
}

// layer-1 mm (f32 input) + atomic-free CSR scatter (src AND dst), role-split.
__global__ __launch_bounds__(256) void mm_fill(const float* __restrict__ in, const float* __restrict__ W,
                                               const float* __restrict__ a_s, const float* __restrict__ a_d,
                                               unsigned* __restrict__ hb, float* __restrict__ as_,
                                               float* __restrict__ ad_, int N, int nbt,
                                               const int* __restrict__ ei, const int* __restrict__ rank, int E,
                                               const int* __restrict__ offs, int* __restrict__ csr_src,
                                               int* __restrict__ csr_dst) {
    int bid = blockIdx.x;
    if (bid < nbt) {
        mm_tile_body<false>(bid, in, W, a_s, a_d, hb, as_, ad_, N);
    } else {
        int i = (bid - nbt) * 256 + threadIdx.x;
        int EP = E + N;
        if (i >= EP) return;
        int s, d;
        if (i < E) { s = ei[i]; d = ei[E + i]; } else { s = i - E; d = i - E; }
        int p = offs[d] + rank[i];
        csr_src[p] = s;
        csr_dst[p] = d;
    }
}

// ---------------- per-node aggregate + bias + l2norm + relu ----------------
// R11 = R8 structure (proven fastest; R10's batched-prefetch rewrite regressed
// -> reverted) with ONE delta: per-edge weight read coalesced from we[]
// (precomputed by edge_w) instead of random as_ gather + expf in the chain.
__global__ __launch_bounds__(256) void gat_agg(const unsigned* __restrict__ hb, const float* __restrict__ we,
                                               const int* __restrict__ offs,
                                               const int* __restrict__ csr, const float* __restrict__ bias,
                                               unsigned* __restrict__ outb, int N) {
    int tid = threadIdx.x, lane = tid & 63, wid = tid >> 6;
    int node = blockIdx.x * 4 + wid;
    if (node >= N) return;
    int start = offs[node], end = offs[node + 1];
    int deg = end - start;

    int src_reg = 0;
    float w_reg = 0.f;
    if (lane < deg) {
        src_reg = csr[start + lane];   // coalesced
        w_reg = we[start + lane];      // coalesced (csr order)
    }

    // pass 2: lane = esub*16+fg; 16 edges/iter, 4 uint2 gathers in flight;
    // lanes >= deg carry w_reg==0 -> contributions auto-masked (src 0 safe).
    int esub = lane >> 4, fg = lane & 15;
    int dmain = deg < 64 ? deg : 64;
    float a0 = 0.f, a1 = 0.f, a2 = 0.f, a3 = 0.f, sw = 0.f;
    for (int i0 = 0; i0 < dmain; i0 += 16) {
        float wA = __shfl(w_reg, i0 + esub);
        int   sA = __shfl(src_reg, i0 + esub);
        float wB = __shfl(w_reg, i0 + 4 + esub);
        int   sB = __shfl(src_reg, i0 + 4 + esub);
        float wC = __shfl(w_reg, i0 + 8 + esub);
        int   sC = __shfl(src_reg, i0 + 8 + esub);
        float wD = __shfl(w_reg, i0 + 12 + esub);
        int   sD = __shfl(src_reg, i0 + 12 + esub);
        const uint2 hA = *(const uint2*)(hb + ((size_t)sA << 5) + (fg << 1));
        const uint2 hB = *(const uint2*)(hb + ((size_t)sB << 5) + (fg << 1));
        const uint2 hC = *(const uint2*)(hb + ((size_t)sC << 5) + (fg << 1));
        const uint2 hD = *(const uint2*)(hb + ((size_t)sD << 5) + (fg << 1));
        sw += wA + wB + wC + wD;
        a0 += wA * bflo(hA.x) + wB * bflo(hB.x) + wC * bflo(hC.x) + wD * bflo(hD.x);
        a1 += wA * bfhi(hA.x) + wB * bfhi(hB.x) + wC * bfhi(hC.x) + wD * bfhi(hD.x);
        a2 += wA * bflo(hA.y) + wB * bflo(hB.y) + wC * bflo(hC.y) + wD * bflo(hD.y);
        a3 += wA * bfhi(hA.y) + wB * bfhi(hB.y) + wC * bfhi(hC.y) + wD * bfhi(hD.y);
    }
    for (int t0 = start + 64; t0 < end; t0 += 4) {        // deg>64 tail (rare)
        int t = t0 + esub;
        float w = 0.f; int src = 0;
        if (t < end) { src = csr[t]; w = we[t]; }
        const uint2 hv = *(const uint2*)(hb + ((size_t)src << 5) + (fg << 1));
        sw += w;
        a0 += w * bflo(hv.x); a1 += w * bfhi(hv.x);
        a2 += w * bflo(hv.y); a3 += w * bfhi(hv.y);
    }
    #pragma unroll
    for (int d = 16; d <= 32; d <<= 1) {
        a0 += __shfl_xor(a0, d); a1 += __shfl_xor(a1, d);
        a2 += __shfl_xor(a2, d); a3 += __shfl_xor(a3, d);
        sw += __shfl_xor(sw, d);
    }
    float inv = 1.f / (sw + 1e-16f);
    const float4 bv = *(const float4*)(bias + (fg << 2));
    float o0 = a0 * inv + bv.x, o1 = a1 * inv + bv.y, o2 = a2 * inv + bv.z, o3 = a3 * inv + bv.w;
    float n2 = o0 * o0 + o1 * o1 + o2 * o2 + o3 * o3;
    #pragma unroll
    for (int d = 1; d <= 8; d <<= 1) n2 += __shfl_xor(n2, d);   // across fg groups
    float innrm = 1.f / fmaxf(sqrtf(n2), 1e-12f);
    if (esub == 0) {
        uint2 o;
        o.x = bfpack(fmaxf(o0 * innrm, 0.f), fmaxf(o1 * innrm, 0.f));
        o.y = bfpack(fmaxf(o2 * innrm, 0.f), fmaxf(o3 * innrm, 0.f));
        *(uint2*)(outb + ((size_t)node << 5) + (fg << 1)) = o;
    }
}

// ---------------- fused global_add_pool + MLP + log_softmax ----------------
__global__ __launch_bounds__(256) void pool_mlp(const unsigned short* __restrict__ hb, const int* __restrict__ gstart,
                                                const float* __restrict__ fc1w, const float* __restrict__ fc1b,
                                                const float* __restrict__ fc2w, const float* __restrict__ fc2b,
                                                float* __restrict__ out) {
    __shared__ float W1[DIM * DIM];
    __shared__ float red[4 * DIM];
    __shared__ float tbuf[DIM];
    __shared__ float obuf[CNUM];
    int tid = threadIdx.x, lane = tid & 63, wv = tid >> 6;
    int gid = blockIdx.x;

    const float4* W4 = (const float4*)fc1w;
    float4* W1s = (float4*)W1;
    #pragma unroll
    for (int i = 0; i < 4; ++i) W1s[tid + 256 * i] = W4[tid + 256 * i];

    int s = gstart[gid], e = gstart[gid + 1];
    float acc = 0.f;
    for (int i = s + wv; i < e; i += 4) acc += bfs(hb[((size_t)i << 6) + lane]);
    red[wv * DIM + lane] = acc;
    __syncthreads();

    if (wv == 0) {
        float g = red[lane] + red[DIM + lane] + red[2 * DIM + lane] + red[3 * DIM + lane];
        float t = fc1b[lane];
        #pragma unroll
        for (int k = 0; k < DIM; ++k) t += __shfl(g, k) * W1[k * DIM + lane];
        t = fmaxf(t, 0.f);
        tbuf[lane] = t;
        float o = 0.f;
        if (lane < CNUM) {
            o = fc2b[lane];
            #pragma unroll
            for (int k = 0; k < DIM; ++k) o += tbuf[k] * fc2w[k * CNUM + lane];
            obuf[lane] = o;
        }
        if (lane < CNUM) {
            float mx = obuf[0];
            #pragma unroll
            for (int k = 1; k < CNUM; ++k) mx = fmaxf(mx, obuf[k]);
            float ssum = 0.f;
            #pragma unroll
            for (int k = 0; k < CNUM; ++k) ssum += expf(obuf[k] - mx);
            out[gid * CNUM + lane] = o - mx - logf(ssum);
        }
    }
}

// ---------------- launch ----------------
static inline size_t align256(size_t x) { return (x + 255) & ~size_t(255); }

extern "C" void kernel_launch(void* const* d_in, const int* in_sizes, int n_in,
                              void* d_out, int out_size, void* d_ws, size_t ws_size,
                              hipStream_t stream) {
    const float* x     = (const float*)d_in[0];
    const int*   ei    = (const int*)d_in[1];
    const int*   batch = (const int*)d_in[2];
    const float* w1  = (const float*)d_in[3];
    const float* as1 = (const float*)d_in[4];
    const float* ad1 = (const float*)d_in[5];
    const float* b1  = (const float*)d_in[6];
    const float* w2  = (const float*)d_in[7];
    const float* as2 = (const float*)d_in[8];
    const float* ad2 = (const float*)d_in[9];
    const float* b2  = (const float*)d_in[10];
    const float* w3  = (const float*)d_in[11];
    const float* as3 = (const float*)d_in[12];
    const float* ad3 = (const float*)d_in[13];
    const float* b3  = (const float*)d_in[14];
    const float* fc1w = (const float*)d_in[15];
    const float* fc1b = (const float*)d_in[16];
    const float* fc2w = (const float*)d_in[17];
    const float* fc2b = (const float*)d_in[18];
    float* out = (float*)d_out;

    int N  = in_sizes[0] / DIM;
    int E  = in_sizes[1] / 2;
    int EP = E + N;
    int nb = (N + 255) / 256;   // scan blocks (<= 256 for N <= 65536)

    // workspace carve
    char* p = (char*)d_ws;
    unsigned* hbf = (unsigned*)p; p += align256(sizeof(unsigned) * (size_t)N * (DIM / 2));
    unsigned* oAb = (unsigned*)p; p += align256(sizeof(unsigned) * (size_t)N * (DIM / 2));
    unsigned* oBb = (unsigned*)p; p += align256(sizeof(unsigned) * (size_t)N * (DIM / 2));
    float* as_  = (float*)p; p += align256(sizeof(float) * (size_t)N);
    float* ad_  = (float*)p; p += align256(sizeof(float) * (size_t)N);
    int*   deg  = (int*)p;   p += align256(sizeof(int) * (size_t)N);
    int*   offs = (int*)p;   p += align256(sizeof(int) * (size_t)(N + 1));
    int*   rank = (int*)p;   p += align256(sizeof(int) * (size_t)EP);
    int*   csr  = (int*)p;   p += align256(sizeof(int) * (size_t)EP);
    int*   cdst = (int*)p;   p += align256(sizeof(int) * (size_t)EP);
    float* we   = (float*)p; p += align256(sizeof(float) * (size_t)EP);
    int*   part = (int*)p;   p += align256(sizeof(int) * (size_t)nb);
    int*   gst  = (int*)p;   p += align256(sizeof(int) * (size_t)(GNUM + 1));

    int nblk = (N + 3) / 4;
    int nbt = (N + 63) / 64;    // mm tiles
    int epBlocks = (EP + 255) / 256;

    // CSR build (dst-grouped; layer-invariant)
    hipMemsetAsync(deg, 0, sizeof(int) * (size_t)N, stream);
    deg_rank_kernel<<<epBlocks, 256, 0, stream>>>(ei, E, N, deg, rank);
    scan_misc<<<nb + 1, 256, 0, stream>>>(deg, part, N, nb, batch, N, gst);
    scan_down<<<nb, 256, 0, stream>>>(deg, part, offs, N);

    // layer 1 (mm + CSR scatter overlapped)
    mm_fill<<<nbt + epBlocks, 256, 0, stream>>>(x, w1, as1, ad1, hbf, as_, ad_, N, nbt,
                                                ei, rank, E, offs, csr, cdst);
    edge_w<<<epBlocks, 256, 0, stream>>>(csr, cdst, as_, ad_, we, EP);
    gat_agg<<<nblk, 256, 0, stream>>>(hbf, we, offs, csr, b1, oAb, N);
    // layer 2
    mm_tile_bf<<<nbt, 256, 0, stream>>>(oAb, w2, as2, ad2, hbf, as_, ad_, N);
    edge_w<<<epBlocks, 256, 0, stream>>>(csr, cdst, as_, ad_, we, EP);
    gat_agg<<<nblk, 256, 0, stream>>>(hbf, we, offs, csr, b2, oBb, N);
    // layer 3
    mm_tile_bf<<<nbt, 256, 0, stream>>>(oBb, w3, as3, ad3, hbf, as_, ad_, N);
    edge_w<<<epBlocks, 256, 0, stream>>>(csr, cdst, as_, ad_, we, EP);
    gat_agg<<<nblk, 256, 0, stream>>>(hbf, we, offs, csr, b3, oAb, N);

    // fused pool + head (bf16 input)
    pool_mlp<<<GNUM, 256, 0, stream>>>((const unsigned short*)oAb, gst, fc1w, fc1b, fc2w, fc2b, out);
}

// Round 12
// 286.037 us; speedup vs baseline: 1.0585x; 1.0585x over previous
//
#include <hip/hip_runtime.h>
#include <hip/hip_bf16.h>
#include <math.h>

#define DIM 64
#define GNUM 256
#define CNUM 10

// bf16x2 pack/unpack (RNE). All intermediates (h, layer outputs) are bf16 for
// traffic; alpha/softmax math stays f32 (as_/ad_ from f32 accumulators).
__device__ __forceinline__ unsigned bfpack(float a, float b) {
    unsigned ua = __builtin_bit_cast(unsigned, a);
    unsigned ub = __builtin_bit_cast(unsigned, b);
    ua += 0x7fffu + ((ua >> 16) & 1u);
    ub += 0x7fffu + ((ub >> 16) & 1u);
    return (ua >> 16) | (ub & 0xffff0000u);
}
__device__ __forceinline__ float bflo(unsigned u) { return __builtin_bit_cast(float, u << 16); }
__device__ __forceinline__ float bfhi(unsigned u) { return __builtin_bit_cast(float, u & 0xffff0000u); }
__device__ __forceinline__ float bfs(unsigned short u) { return __builtin_bit_cast(float, (unsigned)u << 16); }

// ---------------- CSR build ----------------
__global__ void deg_rank_kernel(const int* __restrict__ ei, int E, int N,
                                int* __restrict__ deg, int* __restrict__ rank) {
    int i = blockIdx.x * blockDim.x + threadIdx.x;
    int EP = E + N;
    if (i >= EP) return;
    int d = (i < E) ? ei[E + i] : (i - E);   // row 1 of edge_index = dst; self loops appended
    rank[i] = atomicAdd(&deg[d], 1);
}

// scan_blocks + graph_bounds, role-split by blockIdx.
__global__ __launch_bounds__(256) void scan_misc(const int* __restrict__ deg, int* __restrict__ part, int n, int nb,
                                                 const int* __restrict__ batch, int N,
                                                 int* __restrict__ gstart) {
    int bid = blockIdx.x;
    if (bid < nb) {
        __shared__ int ws[4];
        int i = bid * 256 + threadIdx.x;
        int v = (i < n) ? deg[i] : 0;
        #pragma unroll
        for (int d = 32; d >= 1; d >>= 1) v += __shfl_xor(v, d);
        if ((threadIdx.x & 63) == 0) ws[threadIdx.x >> 6] = v;
        __syncthreads();
        if (threadIdx.x == 0) part[bid] = ws[0] + ws[1] + ws[2] + ws[3];
    } else {
        for (int g = threadIdx.x; g <= GNUM; g += 256) {
            int lo = 0, hi = N;
            while (lo < hi) { int mid = (lo + hi) >> 1; if (batch[mid] < g) lo = mid + 1; else hi = mid; }
            gstart[g] = lo;
        }
    }
}

// scan_down with the top-level scan fused (nb <= 256 for N <= 65536).
__global__ __launch_bounds__(256) void scan_down(const int* __restrict__ deg, const int* __restrict__ part,
                                                 int* __restrict__ offs, int n) {
    __shared__ int ws[4];
    __shared__ int base_s;
    int tid = threadIdx.x, lane = tid & 63, wid = tid >> 6;
    int pv = (tid < (int)blockIdx.x) ? part[tid] : 0;
    #pragma unroll
    for (int d = 32; d >= 1; d >>= 1) pv += __shfl_xor(pv, d);
    if (lane == 0) ws[wid] = pv;
    __syncthreads();
    if (tid == 0) base_s = ws[0] + ws[1] + ws[2] + ws[3];
    __syncthreads();
    int i = blockIdx.x * 256 + tid;
    int v = (i < n) ? deg[i] : 0;
    int x = v;
    #pragma unroll
    for (int d = 1; d < 64; d <<= 1) { int t = __shfl_up(x, d); if (lane >= d) x += t; }
    if (lane == 63) ws[wid] = x;
    __syncthreads();
    int add = base_s;
    for (int w = 0; w < wid; ++w) add += ws[w];
    if (i < n) offs[i] = add + x - v;
    if (i == n - 1) offs[n] = add + x;
}

// ---------------- tiled mm body ----------------
// 64x64 tile per block; x transposed into LDS (stride 68 floats). 4x4 register
// tile per thread. Input either f32 (layer 1) or packed bf16 (layers 2,3);
// h output always packed bf16 (R7: halves dominant gather traffic).
#define XSTR 68
template<bool BF16IN>
__device__ __forceinline__ void mm_tile_body(int bid,
                                             const void* __restrict__ in_, const float* __restrict__ W,
                                             const float* __restrict__ a_s, const float* __restrict__ a_d,
                                             unsigned* __restrict__ hb, float* __restrict__ as_,
                                             float* __restrict__ ad_, int N) {
    __shared__ float Ws[DIM * DIM];
    __shared__ float xT[XSTR * DIM];
    int tid = threadIdx.x;
    int base = bid * 64;

    const float4* W4 = (const float4*)W;
    float4* Ws4 = (float4*)Ws;
    #pragma unroll
    for (int i = 0; i < 4; ++i) Ws4[tid + 256 * i] = W4[tid + 256 * i];

    {
        int row = tid >> 2;
        int kb = (tid & 3) << 4;
        int grow = base + row;
        int crow = grow < N ? grow : N - 1;
        if (BF16IN) {
            const unsigned* xr = (const unsigned*)in_ + ((size_t)crow << 5) + (kb >> 1);
            uint4 u0 = *(const uint4*)xr;
            uint4 u1 = *(const uint4*)(xr + 4);
            xT[(kb + 0) * XSTR + row] = bflo(u0.x);  xT[(kb + 1) * XSTR + row] = bfhi(u0.x);
            xT[(kb + 2) * XSTR + row] = bflo(u0.y);  xT[(kb + 3) * XSTR + row] = bfhi(u0.y);
            xT[(kb + 4) * XSTR + row] = bflo(u0.z);  xT[(kb + 5) * XSTR + row] = bfhi(u0.z);
            xT[(kb + 6) * XSTR + row] = bflo(u0.w);  xT[(kb + 7) * XSTR + row] = bfhi(u0.w);
            xT[(kb + 8) * XSTR + row] = bflo(u1.x);  xT[(kb + 9) * XSTR + row] = bfhi(u1.x);
            xT[(kb + 10) * XSTR + row] = bflo(u1.y); xT[(kb + 11) * XSTR + row] = bfhi(u1.y);
            xT[(kb + 12) * XSTR + row] = bflo(u1.z); xT[(kb + 13) * XSTR + row] = bfhi(u1.z);
            xT[(kb + 14) * XSTR + row] = bflo(u1.w); xT[(kb + 15) * XSTR + row] = bfhi(u1.w);
        } else {
            const float4* xr = (const float4*)((const float*)in_ + ((size_t)crow << 6) + kb);
            float4 v0 = xr[0], v1 = xr[1], v2 = xr[2], v3 = xr[3];
            xT[(kb + 0) * XSTR + row] = v0.x;  xT[(kb + 1) * XSTR + row] = v0.y;
            xT[(kb + 2) * XSTR + row] = v0.z;  xT[(kb + 3) * XSTR + row] = v0.w;
            xT[(kb + 4) * XSTR + row] = v1.x;  xT[(kb + 5) * XSTR + row] = v1.y;
            xT[(kb + 6) * XSTR + row] = v1.z;  xT[(kb + 7) * XSTR + row] = v1.w;
            xT[(kb + 8) * XSTR + row] = v2.x;  xT[(kb + 9) * XSTR + row] = v2.y;
            xT[(kb + 10) * XSTR + row] = v2.z; xT[(kb + 11) * XSTR + row] = v2.w;
            xT[(kb + 12) * XSTR + row] = v3.x; xT[(kb + 13) * XSTR + row] = v3.y;
            xT[(kb + 14) * XSTR + row] = v3.z; xT[(kb + 15) * XSTR + row] = v3.w;
        }
    }
    __syncthreads();

    int tx = tid & 15, ty = tid >> 4;
    int c0 = tx << 2, r0 = ty << 2;
    float acc[4][4] = {{0.f}};
    #pragma unroll 8
    for (int k = 0; k < DIM; ++k) {
        float4 xv = *(const float4*)(xT + k * XSTR + r0);
        float4 wv = *(const float4*)(Ws + k * DIM + c0);
        acc[0][0] += xv.x * wv.x; acc[0][1] += xv.x * wv.y; acc[0][2] += xv.x * wv.z; acc[0][3] += xv.x * wv.w;
        acc[1][0] += xv.y * wv.x; acc[1][1] += xv.y * wv.y; acc[1][2] += xv.y * wv.z; acc[1][3] += xv.y * wv.w;
        acc[2][0] += xv.z * wv.x; acc[2][1] += xv.z * wv.y; acc[2][2] += xv.z * wv.z; acc[2][3] += xv.z * wv.w;
        acc[3][0] += xv.w * wv.x; acc[3][1] += xv.w * wv.y; acc[3][2] += xv.w * wv.z; acc[3][3] += xv.w * wv.w;
    }

    float4 av = *(const float4*)(a_s + c0);
    float4 dv = *(const float4*)(a_d + c0);
    #pragma unroll
    for (int ri = 0; ri < 4; ++ri) {
        int grow = base + r0 + ri;
        float s1 = acc[ri][0] * av.x + acc[ri][1] * av.y + acc[ri][2] * av.z + acc[ri][3] * av.w;
        float s2 = acc[ri][0] * dv.x + acc[ri][1] * dv.y + acc[ri][2] * dv.z + acc[ri][3] * dv.w;
        #pragma unroll
        for (int d = 1; d <= 8; d <<= 1) { s1 += __shfl_xor(s1, d); s2 += __shfl_xor(s2, d); }
        if (grow < N) {
            uint2 o;
            o.x = bfpack(acc[ri][0], acc[ri][1]);
            o.y = bfpack(acc[ri][2], acc[ri][3]);
            *(uint2*)(hb + ((size_t)grow << 5) + (tx << 1)) = o;
            if (tx == 0) { as_[grow] = s1; ad_[grow] = s2; }
        }
    }
}

__global__ __launch_bounds__(256) void mm_tile_bf(const unsigned* __restrict__ in, const float* __restrict__ W,
                                                  const float* __restrict__ a_s, const float* __restrict__ a_d,
                                                  unsigned* __restrict__ hb, float* __restrict__ as_,
                                                  float* __restrict__ ad_, int N) {
    mm_tile_body<true>(blockIdx.x, in, W, a_s, a_d, hb, as_, ad_, N);
}

// layer-1 mm (f32 input) + atomic-free CSR scatter, role-split.
__global__ __launch_bounds__(256) void mm_fill(const float* __restrict__ in, const float* __restrict__ W,
                                               const float* __restrict__ a_s, const float* __restrict__ a_d,
                                               unsigned* __restrict__ hb, float* __restrict__ as_,
                                               float* __restrict__ ad_, int N, int nbt,
                                               const int* __restrict__ ei, const int* __restrict__ rank, int E,
                                               const int* __restrict__ offs, int* __restrict__ csr_src) {
    int bid = blockIdx.x;
    if (bid < nbt) {
        mm_tile_body<false>(bid, in, W, a_s, a_d, hb, as_, ad_, N);
    } else {
        int i = (bid - nbt) * 256 + threadIdx.x;
        int EP = E + N;
        if (i >= EP) return;
        int s, d;
        if (i < E) { s = ei[i]; d = ei[E + i]; } else { s = i - E; d = i - E; }
        csr_src[offs[d] + rank[i]] = s;
    }
}

// ---------------- per-node aggregate: pass 2 + epilogue (R8 structure) ----------------
__device__ __forceinline__ void agg_node(const unsigned* __restrict__ hb, const float* __restrict__ as_,
                                         const int* __restrict__ csr, float adi,
                                         int start, int end, int deg, int src_reg, float w_reg,
                                         const float* __restrict__ bias, unsigned* __restrict__ outb,
                                         int node, int esub, int fg) {
    int dmain = deg < 64 ? deg : 64;
    float a0 = 0.f, a1 = 0.f, a2 = 0.f, a3 = 0.f, sw = 0.f;
    for (int i0 = 0; i0 < dmain; i0 += 16) {
        float wA = __shfl(w_reg, i0 + esub);
        int   sA = __shfl(src_reg, i0 + esub);
        float wB = __shfl(w_reg, i0 + 4 + esub);
        int   sB = __shfl(src_reg, i0 + 4 + esub);
        float wC = __shfl(w_reg, i0 + 8 + esub);
        int   sC = __shfl(src_reg, i0 + 8 + esub);
        float wD = __shfl(w_reg, i0 + 12 + esub);
        int   sD = __shfl(src_reg, i0 + 12 + esub);
        const uint2 hA = *(const uint2*)(hb + ((size_t)sA << 5) + (fg << 1));
        const uint2 hB = *(const uint2*)(hb + ((size_t)sB << 5) + (fg << 1));
        const uint2 hC = *(const uint2*)(hb + ((size_t)sC << 5) + (fg << 1));
        const uint2 hD = *(const uint2*)(hb + ((size_t)sD << 5) + (fg << 1));
        sw += wA + wB + wC + wD;
        a0 += wA * bflo(hA.x) + wB * bflo(hB.x) + wC * bflo(hC.x) + wD * bflo(hD.x);
        a1 += wA * bfhi(hA.x) + wB * bfhi(hB.x) + wC * bfhi(hC.x) + wD * bfhi(hD.x);
        a2 += wA * bflo(hA.y) + wB * bflo(hB.y) + wC * bflo(hC.y) + wD * bflo(hD.y);
        a3 += wA * bfhi(hA.y) + wB * bfhi(hB.y) + wC * bfhi(hC.y) + wD * bfhi(hD.y);
    }
    for (int t0 = start + 64; t0 < end; t0 += 4) {        // deg>64 tail (rare)
        int t = t0 + esub;
        float w = 0.f; int src = 0;
        if (t < end) {
            src = csr[t];
            float e = as_[src] + adi;
            e = (e > 0.f) ? e : 0.2f * e;
            w = expf(e);
        }
        const uint2 hv = *(const uint2*)(hb + ((size_t)src << 5) + (fg << 1));
        sw += w;
        a0 += w * bflo(hv.x); a1 += w * bfhi(hv.x);
        a2 += w * bflo(hv.y); a3 += w * bfhi(hv.y);
    }
    #pragma unroll
    for (int d = 16; d <= 32; d <<= 1) {
        a0 += __shfl_xor(a0, d); a1 += __shfl_xor(a1, d);
        a2 += __shfl_xor(a2, d); a3 += __shfl_xor(a3, d);
        sw += __shfl_xor(sw, d);
    }
    float inv = 1.f / (sw + 1e-16f);
    const float4 bv = *(const float4*)(bias + (fg << 2));
    float o0 = a0 * inv + bv.x, o1 = a1 * inv + bv.y, o2 = a2 * inv + bv.z, o3 = a3 * inv + bv.w;
    float n2 = o0 * o0 + o1 * o1 + o2 * o2 + o3 * o3;
    #pragma unroll
    for (int d = 1; d <= 8; d <<= 1) n2 += __shfl_xor(n2, d);   // across fg groups
    float innrm = 1.f / fmaxf(sqrtf(n2), 1e-12f);
    if (esub == 0) {
        uint2 o;
        o.x = bfpack(fmaxf(o0 * innrm, 0.f), fmaxf(o1 * innrm, 0.f));
        o.y = bfpack(fmaxf(o2 * innrm, 0.f), fmaxf(o3 * innrm, 0.f));
        *(uint2*)(outb + ((size_t)node << 5) + (fg << 1)) = o;
    }
}

// R12: R8 structure (proven best, 280.7us) with TWO independent nodes per
// wave: node B's front-end (csr load -> as_ gather -> exp) is issued together
// with node A's, so B's ~900cyc gather chain overlaps A's pass-2. Unlike R10
// (deeper prefetch of ONE chain, serialized by shfl) this adds a second
// independent chain. Grid halves; no new dispatches (R11's mistake).
__global__ __launch_bounds__(256) void gat_agg(const unsigned* __restrict__ hb, const float* __restrict__ as_,
                                               const float* __restrict__ ad_, const int* __restrict__ offs,
                                               const int* __restrict__ csr, const float* __restrict__ bias,
                                               unsigned* __restrict__ outb, int N) {
    int tid = threadIdx.x, lane = tid & 63, wid = tid >> 6;
    int node0 = blockIdx.x * 8 + wid;
    int node1 = node0 + 4;
    if (node0 >= N) return;
    bool has1 = (node1 < N);

    int start0 = offs[node0], end0 = offs[node0 + 1];
    int start1 = 0, end1 = 0;
    if (has1) { start1 = offs[node1]; end1 = offs[node1 + 1]; }
    int deg0 = end0 - start0, deg1 = end1 - start1;
    float adi0 = ad_[node0];
    float adi1 = has1 ? ad_[node1] : 0.f;

    // front-end: both csr loads issued, then both as_ gathers -> two
    // independent latency chains in flight.
    int s0 = 0, s1 = 0;
    if (lane < deg0) s0 = csr[start0 + lane];
    if (lane < deg1) s1 = csr[start1 + lane];
    float as0 = as_[s0];
    float as1 = as_[s1];
    float w0 = 0.f, w1 = 0.f;
    if (lane < deg0) {
        float e = as0 + adi0;
        e = (e > 0.f) ? e : 0.2f * e;
        w0 = expf(e);
    }
    if (lane < deg1) {
        float e = as1 + adi1;
        e = (e > 0.f) ? e : 0.2f * e;
        w1 = expf(e);
    }

    int esub = lane >> 4, fg = lane & 15;
    agg_node(hb, as_, csr, adi0, start0, end0, deg0, s0, w0, bias, outb, node0, esub, fg);
    if (has1)
        agg_node(hb, as_, csr, adi1, start1, end1, deg1, s1, w1, bias, outb, node1, esub, fg);
}

// ---------------- fused global_add_pool + MLP + log_softmax ----------------
__global__ __launch_bounds__(256) void pool_mlp(const unsigned short* __restrict__ hb, const int* __restrict__ gstart,
                                                const float* __restrict__ fc1w, const float* __restrict__ fc1b,
                                                const float* __restrict__ fc2w, const float* __restrict__ fc2b,
                                                float* __restrict__ out) {
    __shared__ float W1[DIM * DIM];
    __shared__ float red[4 * DIM];
    __shared__ float tbuf[DIM];
    __shared__ float obuf[CNUM];
    int tid = threadIdx.x, lane = tid & 63, wv = tid >> 6;
    int gid = blockIdx.x;

    const float4* W4 = (const float4*)fc1w;
    float4* W1s = (float4*)W1;
    #pragma unroll
    for (int i = 0; i < 4; ++i) W1s[tid + 256 * i] = W4[tid + 256 * i];

    int s = gstart[gid], e = gstart[gid + 1];
    float acc = 0.f;
    for (int i = s + wv; i < e; i += 4) acc += bfs(hb[((size_t)i << 6) + lane]);
    red[wv * DIM + lane] = acc;
    __syncthreads();

    if (wv == 0) {
        float g = red[lane] + red[DIM + lane] + red[2 * DIM + lane] + red[3 * DIM + lane];
        float t = fc1b[lane];
        #pragma unroll
        for (int k = 0; k < DIM; ++k) t += __shfl(g, k) * W1[k * DIM + lane];
        t = fmaxf(t, 0.f);
        tbuf[lane] = t;
        float o = 0.f;
        if (lane < CNUM) {
            o = fc2b[lane];
            #pragma unroll
            for (int k = 0; k < DIM; ++k) o += tbuf[k] * fc2w[k * CNUM + lane];
            obuf[lane] = o;
        }
        if (lane < CNUM) {
            float mx = obuf[0];
            #pragma unroll
            for (int k = 1; k < CNUM; ++k) mx = fmaxf(mx, obuf[k]);
            float ssum = 0.f;
            #pragma unroll
            for (int k = 0; k < CNUM; ++k) ssum += expf(obuf[k] - mx);
            out[gid * CNUM + lane] = o - mx - logf(ssum);
        }
    }
}

// ---------------- launch ----------------
static inline size_t align256(size_t x) { return (x + 255) & ~size_t(255); }

extern "C" void kernel_launch(void* const* d_in, const int* in_sizes, int n_in,
                              void* d_out, int out_size, void* d_ws, size_t ws_size,
                              hipStream_t stream) {
    const float* x     = (const float*)d_in[0];
    const int*   ei    = (const int*)d_in[1];
    const int*   batch = (const int*)d_in[2];
    const float* w1  = (const float*)d_in[3];
    const float* as1 = (const float*)d_in[4];
    const float* ad1 = (const float*)d_in[5];
    const float* b1  = (const float*)d_in[6];
    const float* w2  = (const float*)d_in[7];
    const float* as2 = (const float*)d_in[8];
    const float* ad2 = (const float*)d_in[9];
    const float* b2  = (const float*)d_in[10];
    const float* w3  = (const float*)d_in[11];
    const float* as3 = (const float*)d_in[12];
    const float* ad3 = (const float*)d_in[13];
    const float* b3  = (const float*)d_in[14];
    const float* fc1w = (const float*)d_in[15];
    const float* fc1b = (const float*)d_in[16];
    const float* fc2w = (const float*)d_in[17];
    const float* fc2b = (const float*)d_in[18];
    float* out = (float*)d_out;

    int N  = in_sizes[0] / DIM;
    int E  = in_sizes[1] / 2;
    int EP = E + N;
    int nb = (N + 255) / 256;   // scan blocks (<= 256 for N <= 65536)

    // workspace carve
    char* p = (char*)d_ws;
    unsigned* hbf = (unsigned*)p; p += align256(sizeof(unsigned) * (size_t)N * (DIM / 2));
    unsigned* oAb = (unsigned*)p; p += align256(sizeof(unsigned) * (size_t)N * (DIM / 2));
    unsigned* oBb = (unsigned*)p; p += align256(sizeof(unsigned) * (size_t)N * (DIM / 2));
    float* as_  = (float*)p; p += align256(sizeof(float) * (size_t)N);
    float* ad_  = (float*)p; p += align256(sizeof(float) * (size_t)N);
    int*   deg  = (int*)p;   p += align256(sizeof(int) * (size_t)N);
    int*   offs = (int*)p;   p += align256(sizeof(int) * (size_t)(N + 1));
    int*   rank = (int*)p;   p += align256(sizeof(int) * (size_t)EP);
    int*   csr  = (int*)p;   p += align256(sizeof(int) * (size_t)EP);
    int*   part = (int*)p;   p += align256(sizeof(int) * (size_t)nb);
    int*   gst  = (int*)p;   p += align256(sizeof(int) * (size_t)(GNUM + 1));

    int nblk2 = (N + 7) / 8;    // gat_agg: 2 nodes per wave
    int nbt = (N + 63) / 64;    // mm tiles
    int epBlocks = (EP + 255) / 256;

    // CSR build (dst-grouped; layer-invariant)
    hipMemsetAsync(deg, 0, sizeof(int) * (size_t)N, stream);
    deg_rank_kernel<<<epBlocks, 256, 0, stream>>>(ei, E, N, deg, rank);
    scan_misc<<<nb + 1, 256, 0, stream>>>(deg, part, N, nb, batch, N, gst);
    scan_down<<<nb, 256, 0, stream>>>(deg, part, offs, N);

    // layer 1 (mm + CSR scatter overlapped)
    mm_fill<<<nbt + epBlocks, 256, 0, stream>>>(x, w1, as1, ad1, hbf, as_, ad_, N, nbt,
                                                ei, rank, E, offs, csr);
    gat_agg<<<nblk2, 256, 0, stream>>>(hbf, as_, ad_, offs, csr, b1, oAb, N);
    // layer 2
    mm_tile_bf<<<nbt, 256, 0, stream>>>(oAb, w2, as2, ad2, hbf, as_, ad_, N);
    gat_agg<<<nblk2, 256, 0, stream>>>(hbf, as_, ad_, offs, csr, b2, oBb, N);
    // layer 3
    mm_tile_bf<<<nbt, 256, 0, stream>>>(oBb, w3, as3, ad3, hbf, as_, ad_, N);
    gat_agg<<<nblk2, 256, 0, stream>>>(hbf, as_, ad_, offs, csr, b3, oAb, N);

    // fused pool + head (bf16 input)
    pool_mlp<<<GNUM, 256, 0, stream>>>((const unsigned short*)oAb, gst, fc1w, fc1b, fc2w, fc2b, out);
}